// Round 1
// baseline (780.568 us; speedup 1.0000x reference)
//
#include <hip/hip_runtime.h>
#include <cstdint>
#include <cstddef>

// Algebraic feature expansion: out[B,696] = concat(x[B,16],
//   all 2-subset products (120), all 3-subset products (560)).
// 730 MB out vs 17 MB in -> must be write-BW-bound.
//
// V2 theory: V1 did 12 ds_read_b32 per output float4 (broadcast-heavy,
// LDS-pipe-bound at ~2.9 TB/s). V2 holds each row in 16 VGPRs (one row per
// lane, all indices compile-time constants so the array never spills),
// computes products with pure VALU (~1.3 v_mul per output, CSE'd pairs),
// and uses LDS only as a transpose stage: 1 ds_write_b128 + 1 ds_read_b128
// per output float4 -> ~8x less LDS pipe pressure -> HBM store roofline.

#define NCOLS       16
#define NOUT        696          // 16 + C(16,2)=120 + C(16,3)=560
#define F4_PER_ROW  174          // 696 / 4
#define RPB         64           // rows per block == lanes per wave
#define THREADS     256          // 4 waves; each wave owns a column range
#define CHUNK       58           // f4-columns staged per pass; 174 = 3*58
#define ROWPAD      65           // odd f4 stride -> conflict-free drain reads

typedef float vfloat4 __attribute__((ext_vector_type(4)));

// Compile-time table: for each output column, three 5-bit indices
// (16 = "unused"). Order matches itertools.combinations lexicographic order:
// singles 0..15, then pairs (i<j), then triples (i<j<k).
struct Tab { uint32_t v[NOUT]; };
static constexpr Tab make_tab() {
    Tab T{};
    int n = 0;
    for (uint32_t c = 0; c < NCOLS; ++c)
        T.v[n++] = c | (16u << 8) | (16u << 16);
    for (uint32_t i = 0; i < NCOLS; ++i)
        for (uint32_t j = i + 1; j < NCOLS; ++j)
            T.v[n++] = i | (j << 8) | (16u << 16);
    for (uint32_t i = 0; i < NCOLS; ++i)
        for (uint32_t j = i + 1; j < NCOLS; ++j)
            for (uint32_t k = j + 1; k < NCOLS; ++k)
                T.v[n++] = i | (j << 8) | (k << 16);
    return T;
}
static constexpr Tab HT = make_tab();   // folded at compile time, no mem access

// Product of output column COL from a register-resident row.
// All indices are constexpr -> x[] stays in VGPRs (no scratch).
template<int COL>
__device__ __forceinline__ float prod_col(const float (&x)[NCOLS]) {
    constexpr uint32_t t = HT.v[COL];
    constexpr int a = t & 31;
    constexpr int b = (t >> 8) & 31;
    constexpr int c = (t >> 16) & 31;
    float r = x[a];
    if constexpr (b < NCOLS) r *= x[b];   // compiler CSEs shared x[a]*x[b]
    if constexpr (c < NCOLS) r *= x[c];
    return r;
}

// Unrolled emitter: compute f4 column C and ds_write_b128 it.
// st[c4_local][lane]: lane index contiguous -> each write instr covers a
// contiguous 1 KB LDS span -> conflict-free.
template<int C, int END, int PBASE>
struct Emit {
    static __device__ __forceinline__ void run(const float (&x)[NCOLS],
                                               vfloat4 (&st)[CHUNK][ROWPAD],
                                               int lane) {
        vfloat4 o;
        o.x = prod_col<4 * C + 0>(x);
        o.y = prod_col<4 * C + 1>(x);
        o.z = prod_col<4 * C + 2>(x);
        o.w = prod_col<4 * C + 3>(x);
        st[C - PBASE][lane] = o;
        Emit<C + 1, END, PBASE>::run(x, st, lane);
    }
};
template<int END, int PBASE>
struct Emit<END, END, PBASE> {
    static __device__ __forceinline__ void run(const float (&)[NCOLS],
                                               vfloat4 (&)[CHUNK][ROWPAD], int) {}
};

// Per pass, wave w computes a static sub-range of the 58 f4 columns
// (15+15+14+14) for its lane's row. Branch is wave-uniform.
template<int PBASE>
__device__ __forceinline__ void compute_pass(const float (&x)[NCOLS],
                                             vfloat4 (&st)[CHUNK][ROWPAD],
                                             int w, int lane) {
    if      (w == 0) Emit<PBASE +  0, PBASE + 15, PBASE>::run(x, st, lane);
    else if (w == 1) Emit<PBASE + 15, PBASE + 30, PBASE>::run(x, st, lane);
    else if (w == 2) Emit<PBASE + 30, PBASE + 44, PBASE>::run(x, st, lane);
    else             Emit<PBASE + 44, PBASE + 58, PBASE>::run(x, st, lane);
}

// Drain: g in [0, 58*64): row = g/58 (const-divisor magic), c4 = g%58.
// LDS read stride between lanes = ROWPAD=65 f4 (odd) -> lanes spread evenly
// over the 8 bank-quads -> conflict-free ds_read_b128.
// Stores: contiguous 928 B runs per row chunk, streaming (never re-read).
template<int PBASE>
__device__ __forceinline__ void drain_pass(const vfloat4 (&st)[CHUNK][ROWPAD],
                                           vfloat4* __restrict__ outv,
                                           int tid, int rows_left) {
#pragma unroll
    for (int d = 0; d < 14; ++d) {        // g <= 13*256+255 = 3583 < 3712
        const int g  = d * THREADS + tid;
        const int rl = g / CHUNK;
        const int c4 = g - rl * CHUNK;
        if (rl < rows_left)
            __builtin_nontemporal_store(st[c4][rl],
                &outv[(size_t)rl * F4_PER_ROW + PBASE + c4]);
    }
    {   // tail iteration: g in [3584, 3839], valid while < 3712
        const int g = 14 * THREADS + tid;
        if (g < CHUNK * RPB) {
            const int rl = g / CHUNK;
            const int c4 = g - rl * CHUNK;
            if (rl < rows_left)
                __builtin_nontemporal_store(st[c4][rl],
                    &outv[(size_t)rl * F4_PER_ROW + PBASE + c4]);
        }
    }
}

__global__ __launch_bounds__(THREADS) void algebraic_expand_kernel(
        const float* __restrict__ xg, float* __restrict__ out, int nrows) {
    __shared__ vfloat4 st[CHUNK][ROWPAD];     // 58*65*16 B = 58.9 KB

    const int tid  = threadIdx.x;
    const int lane = tid & 63;
    const int w    = tid >> 6;
    const int r0   = blockIdx.x * RPB;

    // Each lane holds its row in 16 VGPRs. All 4 waves load the same 64 rows
    // (L1-hit redundancy; read traffic is 2% of write traffic).
    float x[NCOLS];
    {
        const int row = r0 + lane;
        if (row < nrows) {
            const vfloat4* xr = (const vfloat4*)xg + (size_t)row * 4;
            const vfloat4 a = xr[0], b = xr[1], c = xr[2], d = xr[3];
            x[0]  = a.x; x[1]  = a.y; x[2]  = a.z; x[3]  = a.w;
            x[4]  = b.x; x[5]  = b.y; x[6]  = b.z; x[7]  = b.w;
            x[8]  = c.x; x[9]  = c.y; x[10] = c.z; x[11] = c.w;
            x[12] = d.x; x[13] = d.y; x[14] = d.z; x[15] = d.w;
        } else {
#pragma unroll
            for (int i = 0; i < NCOLS; ++i) x[i] = 0.0f;
        }
    }

    vfloat4* outv = (vfloat4*)out + (size_t)r0 * F4_PER_ROW;
    const int rem = nrows - r0;
    const int rows_left = rem < RPB ? rem : RPB;

    compute_pass<0>(x, st, w, lane);
    __syncthreads();
    drain_pass<0>(st, outv, tid, rows_left);
    __syncthreads();

    compute_pass<CHUNK>(x, st, w, lane);
    __syncthreads();
    drain_pass<CHUNK>(st, outv, tid, rows_left);
    __syncthreads();

    compute_pass<2 * CHUNK>(x, st, w, lane);
    __syncthreads();
    drain_pass<2 * CHUNK>(st, outv, tid, rows_left);
}

extern "C" void kernel_launch(void* const* d_in, const int* in_sizes, int n_in,
                              void* d_out, int out_size, void* d_ws, size_t ws_size,
                              hipStream_t stream) {
    const float* x = (const float*)d_in[0];
    float* out = (float*)d_out;
    const int nrows = in_sizes[0] / NCOLS;            // 262144
    const int blocks = (nrows + RPB - 1) / RPB;       // 4096
    algebraic_expand_kernel<<<blocks, THREADS, 0, stream>>>(x, out, nrows);
}